// Round 14
// baseline (106.934 us; speedup 1.0000x reference)
//
#include <hip/hip_runtime.h>
#include <math.h>

#define NMAX  4096
#define NT    1024      // 16 waves/block, 1 particle/wave
#define NC    10        // cells per dim, cell size = RADIUS
#define NCELL 1000

// n assumed == 4096 (reference problem size).

constexpr float RADIUS       = 0.1f;
constexpr float DT           = 1.0f / 60.0f;
constexpr float MAX_VEL      = 3.0f;               // 0.5*0.1/DT
constexpr float VISCOSITY    = 60.0f;
constexpr float DENSITY_REST = 17510.1f;
constexpr float STIFFNESS    = 2.99e-11f;
constexpr float EPS          = 1e-8f;
constexpr float SPIKY_C      = (float)(15.0 / (3.14159265358979323846 * 1e-6)); // 15/(pi*R^6)

#define BAR_STRIDE 16   // uints (64 B) between barrier words
#define NGROUPS    16   // 256 blocks / 16 per group

// Persistent barrier words in device BSS: zeroed at module load, never touched
// by the harness (it only poisons d_ws). Counters are MONOTONIC across all
// launches/replays; all barrier logic is RELATIVE to the release value read at
// kernel entry, so no host-side init is needed.
// Layout: [g*16] g=0..15 group arrival counters; [16*16] release counter
// (advances by NGROUPS per phase — each group-last bumps it once; no root level).
__device__ unsigned bar_dev[(NGROUPS + 1) * BAR_STRIDE];

// Device-coherent scalar store (sc1): write-through past the non-coherent
// local L2 so peer XCDs can see it after the barrier.
__device__ __forceinline__ void store_dc(float* p, float v) {
    __hip_atomic_store(p, v, __ATOMIC_RELAXED, __HIP_MEMORY_SCOPE_AGENT);
}

// Device-coherent loads: agent-scope relaxed atomics bypass stale L1/L2 and
// read the coherence point directly (replaces acquire-fence invalidation).
__device__ __forceinline__ float load_dc(const float* p) {
    return __hip_atomic_load(p, __ATOMIC_RELAXED, __HIP_MEMORY_SCOPE_AGENT);
}
__device__ __forceinline__ float4 load_dc4(const float4* p) {
    const unsigned long long* q = (const unsigned long long*)p;
    unsigned long long a = __hip_atomic_load(q,     __ATOMIC_RELAXED, __HIP_MEMORY_SCOPE_AGENT);
    unsigned long long b = __hip_atomic_load(q + 1, __ATOMIC_RELAXED, __HIP_MEMORY_SCOPE_AGENT);
    float4 r;
    ((unsigned long long*)&r)[0] = a;
    ((unsigned long long*)&r)[1] = b;
    return r;
}

// Flat tree barrier, monotonic & relative. Arrival: one LDS-drained
// __syncthreads, then thread 0 RMWs its group counter; group-last RMWs the
// release counter directly (root level removed: one fewer dependent IC round
// trip). Wait: EVERY WAVE polls independently (lane-0 load + wave-uniform
// shfl broadcast) and proceeds as soon as it observes release — no post-poll
// __syncthreads. Safety: the pre-arrival __syncthreads guarantees all waves
// of a block finished the prior phase's LDS reads before ANY block arrives,
// so post-barrier LDS writes by early waves cannot race the prior phase; each
// phase's scatter is followed by its own __syncthreads before cross-wave
// reads. Waves issuing their IC exchange loads immediately on wake overlaps
// load latency with release propagation across waves.
__device__ __forceinline__ void grid_arrive(unsigned phase) {
    __syncthreads();     // drains vmcnt: prior sc1 data stores are at the
                         // coherence point before the flag RMW
    if (threadIdx.x == 0) {
        const unsigned g = (unsigned)blockIdx.x >> 4;   // 16 blocks per group
        unsigned a = __hip_atomic_fetch_add(&bar_dev[g * BAR_STRIDE], 1u,
                                            __ATOMIC_RELAXED, __HIP_MEMORY_SCOPE_AGENT);
        if ((a & 15u) == 15u)                           // last arriver of group
            __hip_atomic_fetch_add(&bar_dev[NGROUPS * BAR_STRIDE], 1u,
                                   __ATOMIC_RELAXED, __HIP_MEMORY_SCOPE_AGENT);
    }
}
__device__ __forceinline__ void grid_wait(unsigned R0, unsigned phase, int lane) {
    const unsigned target = R0 + phase * (unsigned)NGROUPS;
    for (;;) {
        unsigned v = 0;
        if (lane == 0)
            v = __hip_atomic_load(&bar_dev[NGROUPS * BAR_STRIDE],
                                  __ATOMIC_RELAXED, __HIP_MEMORY_SCOPE_AGENT);
        v = __shfl(v, 0);
        if ((int)(v - target) >= 0) break;
        __builtin_amdgcn_s_sleep(1);
    }
}
__device__ __forceinline__ void grid_barrier(unsigned R0, unsigned phase, int lane) {
    grid_arrive(phase);
    grid_wait(R0, phase, lane);
}

__device__ __forceinline__ int cell_coord(float v) {
    int c = (int)floorf(v * 10.f);
    return min(max(c, 0), NC - 1);
}
__device__ __forceinline__ int cell_id(float x, float y, float z) {
    return (cell_coord(x) * NC + cell_coord(y)) * NC + cell_coord(z);
}

// Per-block counting-sort cell list (AoS float4, parallel scan). Rebuilt every
// iteration (exact pair sets required — frozen-order approximation failed R10).
__device__ __forceinline__ int4 build_cells(float4 BX, float4 BY, float4 BZ,
                                            float4* ssp, unsigned* ccnt,
                                            unsigned* wtot, int tid) {
    ccnt[tid] = 0;
    __syncthreads();
    int c0 = cell_id(BX.x, BY.x, BZ.x);
    int c1 = cell_id(BX.y, BY.y, BZ.y);
    int c2 = cell_id(BX.z, BY.z, BZ.z);
    int c3 = cell_id(BX.w, BY.w, BZ.w);
    atomicAdd(&ccnt[c0], 1u); atomicAdd(&ccnt[c1], 1u);
    atomicAdd(&ccnt[c2], 1u); atomicAdd(&ccnt[c3], 1u);
    __syncthreads();
    // all-wave parallel exclusive scan over 1024 entries: thread t = entry t
    {
        const int l = tid & 63, w = tid >> 6;
        unsigned v = ccnt[tid];
        unsigned incl = v;
        for (int off = 1; off < 64; off <<= 1) {
            unsigned u = __shfl_up(incl, off);
            if (l >= off) incl += u;
        }
        if (l == 63) wtot[w] = incl;        // per-wave total
        unsigned excl = incl - v;
        __syncthreads();
        if (tid < 16) {                     // exclusive scan of 16 wave totals
            unsigned tv = wtot[tid];
            unsigned ti = tv;
            for (int off = 1; off < 16; off <<= 1) {
                unsigned u = __shfl_up(ti, off);
                if (tid >= off) ti += u;
            }
            wtot[tid] = ti - tv;
        }
        __syncthreads();
        ccnt[tid] = excl + wtot[w];         // global exclusive start
    }
    __syncthreads();
    int4 p;
    p.x = (int)atomicAdd(&ccnt[c0], 1u); ssp[p.x] = make_float4(BX.x, BY.x, BZ.x, 0.f);
    p.y = (int)atomicAdd(&ccnt[c1], 1u); ssp[p.y] = make_float4(BX.y, BY.y, BZ.y, 0.f);
    p.z = (int)atomicAdd(&ccnt[c2], 1u); ssp[p.z] = make_float4(BX.z, BY.z, BZ.z, 0.f);
    p.w = (int)atomicAdd(&ccnt[c3], 1u); ssp[p.w] = make_float4(BX.w, BY.w, BZ.w, 0.f);
    __syncthreads();          // ccnt now holds cell END offsets; sorted array ready
    return p;
}

// Per-lane run boundaries for the FLATTENED neighborhood walk: lanes are
// partitioned across the 9 (dx,dy) z-column runs (7 lanes per run; lane 63
// idle). Computed ONCE per iteration and reused for rho AND delta walks.
__device__ __forceinline__ void walk_bounds(int cix, int ciy, int ciz,
                                            const unsigned* ccnt, int lane,
                                            int& wbeg, int& wend) {
    const int r = lane / 7;              // run 0..8 (lane 63 -> 9: idle)
    wbeg = 0; wend = 0;
    if (r < 9) {
        const int nx = cix + (r / 3) - 1;
        const int ny = ciy + (r % 3) - 1;
        if ((unsigned)nx < (unsigned)NC && (unsigned)ny < (unsigned)NC) {
            const int zlo = max(ciz - 1, 0), zhi = min(ciz + 1, NC - 1);
            const int cb  = (nx * NC + ny) * NC;
            const int cA  = cb + zlo, cB = cb + zhi;
            wbeg = (cA > 0) ? (int)ccnt[cA - 1] : 0;
            wend = (int)ccnt[cB];
        }
    }
}

// ---------------- single fused kernel ----------------
// 256 blocks x 1024 threads (16 waves), 1 particle/wave, ~132 KB static LDS
// -> 1 block/CU, grid 256 = CU count, co-resident (plain launch).

__global__ __launch_bounds__(NT) void k_fused(const float4* __restrict__ locs4,
                                              const float4* __restrict__ vel4,
                                              const float* __restrict__ locs,
                                              const float* __restrict__ vel,
                                              float* __restrict__ px, float* __restrict__ py,
                                              float* __restrict__ pz,
                                              float* __restrict__ lam,
                                              float* __restrict__ vnx, float* __restrict__ vny,
                                              float* __restrict__ vnz,
                                              float* __restrict__ out, int n) {
    __shared__ float4 ssp[NMAX];        // 64 KB sorted (x,y,z,lam)
    __shared__ float4 svp[NMAX];        // 64 KB sorted (vx,vy,vz,0) for visc
    __shared__ unsigned ccnt[NT];       // 4 KB cell table (+pad)
    __shared__ unsigned wtot[16];       // wave totals for scan

    const int tid  = threadIdx.x;
    const int lane = tid & 63;
    const int wave = tid >> 6;
    const int i    = blockIdx.x * 16 + wave;            // owned particle (original idx)
    const int wo   = lane - (lane / 7) * 7;             // offset within walk run
    unsigned phase = 0;
    (void)n;

    // Per-wave release base, read BEFORE any arrival (every wave's read
    // happens-before this block's arrival via the pre-arrival __syncthreads,
    // and release for phase 1 cannot advance until this block arrives).
    unsigned R0 = 0;
    if (lane == 0)
        R0 = __hip_atomic_load(&bar_dev[NGROUPS * BAR_STRIDE],
                               __ATOMIC_RELAXED, __HIP_MEMORY_SCOPE_AGENT);
    R0 = __shfl(R0, 0);

    // ---- predict (registers) for this thread's 4 particles; build cell list 1 ----
    float4 BX, BY, BZ;
    {
        float lo[12], ve[12];
        *(float4*)&lo[0] = locs4[3*tid];   *(float4*)&lo[4] = locs4[3*tid+1]; *(float4*)&lo[8] = locs4[3*tid+2];
        *(float4*)&ve[0] = vel4[3*tid];    *(float4*)&ve[4] = vel4[3*tid+1];  *(float4*)&ve[8] = vel4[3*tid+2];
        float P[12];
#pragma unroll
        for (int q = 0; q < 4; ++q) {
            float vx = ve[3*q], vy = ve[3*q+1] - 9.8f * DT, vz = ve[3*q+2];
            float vv = sqrtf(vx*vx + vy*vy + vz*vz);
            float s  = fminf(MAX_VEL / (vv + 1e-4f), 1.0f);
            P[3*q]   = lo[3*q]   + DT * vx * s;
            P[3*q+1] = lo[3*q+1] + DT * vy * s;
            P[3*q+2] = lo[3*q+2] + DT * vz * s;
        }
        BX = make_float4(P[0], P[3], P[6], P[9]);
        BY = make_float4(P[1], P[4], P[7], P[10]);
        BZ = make_float4(P[2], P[5], P[8], P[11]);
    }
    int4 p = build_cells(BX, BY, BZ, ssp, ccnt, wtot, tid);

    // own predicted position (identical expression tree -> identical rounding)
    float xi, yi, zi;
    {
        float vx = vel[3*i], vy = vel[3*i+1] - 9.8f * DT, vz = vel[3*i+2];
        float vv = sqrtf(vx*vx + vy*vy + vz*vz);
        float s  = fminf(MAX_VEL / (vv + 1e-4f), 1.0f);
        xi = locs[3*i]   + DT * vx * s;
        yi = locs[3*i+1] + DT * vy * s;
        zi = locs[3*i+2] + DT * vz * s;
    }

    for (int it = 0; it < 3; ++it) {
        const bool last = (it == 2);

        // per-iteration walk boundaries (reused by rho AND delta)
        int wbeg, wend;
        walk_bounds(cell_coord(xi), cell_coord(yi), cell_coord(zi), ccnt, lane, wbeg, wend);

        // ---- rho: flattened neighbor-cell walk ----
        float S = 0.f;
        for (int j = wbeg + wo; j < wend; j += 7) {
            float4 P = ssp[j];
            float ddx = xi - P.x, ddy = yi - P.y, ddz = zi - P.z;
            float d2 = fmaf(ddx,ddx,EPS); d2 = fmaf(ddy,ddy,d2); d2 = fmaf(ddz,ddz,d2);
            float t  = fmaxf(RADIUS - __builtin_amdgcn_sqrtf(d2), 0.f);
            S = fmaf(t*t, t, S);
        }
        for (int off = 32; off > 0; off >>= 1) S += __shfl_down(S, off);
        if (lane == 0) {
            const float ts  = RADIUS - __builtin_amdgcn_sqrtf(EPS);  // exact self-term
            const float TS3 = ts*ts*ts;
            const float k3  = 3.f * SPIKY_C * STIFFNESS;             // L = -3C*lam
            store_dc(&lam[i], k3 * (SPIKY_C * (S - TS3) - DENSITY_REST));
        }
        grid_barrier(R0, ++phase, lane);

        // ---- stage L into .w of sorted slots (coherent sc1 reads, issued
        //      per-wave immediately on barrier wake) ----
        {
            float4 l4 = load_dc4(((const float4*)lam) + tid);
            ssp[p.x].w = l4.x; ssp[p.y].w = l4.y; ssp[p.z].w = l4.z; ssp[p.w].w = l4.w;
        }
        float Li = load_dc(&lam[i]);
        __syncthreads();

        // ---- delta: same boundaries, (x,y,z,L) in one b128 ----
        float ax = 0.f, ay = 0.f, az = 0.f;
        for (int j = wbeg + wo; j < wend; j += 7) {
            float4 P = ssp[j];
            float ddx = xi - P.x, ddy = yi - P.y, ddz = zi - P.z;
            float d2 = fmaf(ddx,ddx,EPS); d2 = fmaf(ddy,ddy,d2); d2 = fmaf(ddz,ddz,d2);
            float rinv = __builtin_amdgcn_rsqf(d2);
            float t  = fmaxf(RADIUS - d2*rinv, 0.f);
            float cf = (Li + P.w) * (t*t) * rinv;
            ax = fmaf(cf, ddx, ax); ay = fmaf(cf, ddy, ay); az = fmaf(cf, ddz, az);
        }
        for (int off = 32; off > 0; off >>= 1) {
            ax += __shfl_down(ax, off); ay += __shfl_down(ay, off); az += __shfl_down(az, off);
        }
        if (lane == 0) {
            float nx = xi + ax, ny = yi + ay, nz = zi + az;
            store_dc(&px[i], nx); store_dc(&py[i], ny); store_dc(&pz[i], nz);
            if (last) {
                out[3*i+0] = nx; out[3*i+1] = ny; out[3*i+2] = nz;
                store_dc(&vnx[i], (nx - locs[3*i+0]) * (1.0f/DT));
                store_dc(&vny[i], (ny - locs[3*i+1]) * (1.0f/DT));
                store_dc(&vnz[i], (nz - locs[3*i+2]) * (1.0f/DT));
            }
        }
        grid_barrier(R0, ++phase, lane);

        // ---- rebuild cell list from updated pred (coherent sc1 reads) ----
        BX = load_dc4(((const float4*)px) + tid);
        BY = load_dc4(((const float4*)py) + tid);
        BZ = load_dc4(((const float4*)pz) + tid);
        p  = build_cells(BX, BY, BZ, ssp, ccnt, wtot, tid);
        xi = load_dc(&px[i]); yi = load_dc(&py[i]); zi = load_dc(&pz[i]);
    }

    // ---- XSPH viscosity: stage new_vel sorted (AoS), then flattened walk ----
    {
        float4 a4 = load_dc4(((const float4*)vnx) + tid);
        float4 b4 = load_dc4(((const float4*)vny) + tid);
        float4 c4 = load_dc4(((const float4*)vnz) + tid);
        svp[p.x] = make_float4(a4.x, b4.x, c4.x, 0.f);
        svp[p.y] = make_float4(a4.y, b4.y, c4.y, 0.f);
        svp[p.z] = make_float4(a4.z, b4.z, c4.z, 0.f);
        svp[p.w] = make_float4(a4.w, b4.w, c4.w, 0.f);
    }
    const float vix = load_dc(&vnx[i]), viy = load_dc(&vny[i]), viz = load_dc(&vnz[i]);
    __syncthreads();

    int wbeg, wend;
    walk_bounds(cell_coord(xi), cell_coord(yi), cell_coord(zi), ccnt, lane, wbeg, wend);
    float sw = 0.f, sax = 0.f, say = 0.f, saz = 0.f;
    for (int j = wbeg + wo; j < wend; j += 7) {
        float4 P = ssp[j];
        float4 V = svp[j];
        float ddx = xi - P.x, ddy = yi - P.y, ddz = zi - P.z;
        float d2 = fmaf(ddx,ddx,EPS); d2 = fmaf(ddy,ddy,d2); d2 = fmaf(ddz,ddz,d2);
        float t  = fmaxf(RADIUS - __builtin_amdgcn_sqrtf(d2), 0.f);
        float w  = t*t*t;
        sw += w;
        sax = fmaf(w, V.x, sax); say = fmaf(w, V.y, say); saz = fmaf(w, V.z, saz);
    }
    for (int off = 32; off > 0; off >>= 1) {
        sw  += __shfl_down(sw, off);  sax += __shfl_down(sax, off);
        say += __shfl_down(say, off); saz += __shfl_down(saz, off);
    }
    if (lane == 0) {
        constexpr float K = VISCOSITY * DT / DENSITY_REST;
        const float KC = K * SPIKY_C;   // C folded here; self-term cancels exactly
        float nvx = vix + KC * (sax - sw * vix);
        float nvy = viy + KC * (say - sw * viy);
        float nvz = viz + KC * (saz - sw * viz);
        float vv = sqrtf(nvx*nvx + nvy*nvy + nvz*nvz);
        float s  = fminf(MAX_VEL / (vv + 1e-4f), 1.0f);
        out[3*NMAX + 3*i + 0] = nvx * s;
        out[3*NMAX + 3*i + 1] = nvy * s;
        out[3*NMAX + 3*i + 2] = nvz * s;
    }
}

extern "C" void kernel_launch(void* const* d_in, const int* in_sizes, int n_in,
                              void* d_out, int out_size, void* d_ws, size_t ws_size,
                              hipStream_t stream) {
    const float* locs = (const float*)d_in[0];
    const float* vel  = (const float*)d_in[1];
    const float4* locs4 = (const float4*)locs;
    const float4* vel4  = (const float4*)vel;
    float* out = (float*)d_out;
    int n = in_sizes[0] / 3;   // 4096

    float* w = (float*)d_ws;
    float* px  = w;        float* py  = px + n;   float* pz  = py + n;
    float* lam = pz + n;
    float* vnx = lam + n;  float* vny = vnx + n;  float* vnz = vny + n;

    int nb = n / 16;   // 16 waves/block, 1 particle/wave -> 256 blocks

    k_fused<<<dim3(nb), dim3(NT), 0, stream>>>(locs4, vel4, locs, vel,
                                               px, py, pz, lam,
                                               vnx, vny, vnz,
                                               out, n);
}

// Round 15
// 103.158 us; speedup vs baseline: 1.0366x; 1.0366x over previous
//
#include <hip/hip_runtime.h>
#include <math.h>

#define NMAX  4096
#define NT    1024      // 16 waves/block, 1 particle/wave
#define NC    10        // cells per dim, cell size = RADIUS
#define NCELL 1000

// n assumed == 4096 (reference problem size).

constexpr float RADIUS       = 0.1f;
constexpr float DT           = 1.0f / 60.0f;
constexpr float MAX_VEL      = 3.0f;               // 0.5*0.1/DT
constexpr float VISCOSITY    = 60.0f;
constexpr float DENSITY_REST = 17510.1f;
constexpr float STIFFNESS    = 2.99e-11f;
constexpr float EPS          = 1e-8f;
constexpr float SPIKY_C      = (float)(15.0 / (3.14159265358979323846 * 1e-6)); // 15/(pi*R^6)

#define BAR_STRIDE 16   // uints (64 B) between barrier words
#define NGROUPS    16   // 256 blocks / 16 per group

// Persistent barrier words in device BSS: zeroed at module load, never touched
// by the harness (it only poisons d_ws). Counters are MONOTONIC across all
// launches/replays; all barrier logic is RELATIVE to the release value read at
// kernel entry, so no host-side init (no memset dispatch) is needed.
// R14 lesson: keep the ROOT level (isolates arrival RMWs from the polled
// release line: 1 write/phase there) and thread-0-only polling (256 readers,
// not 4096) — both alternatives measured slower.
__device__ unsigned bar_dev[(NGROUPS + 2) * BAR_STRIDE];

// Device-coherent scalar store (sc1): write-through past the non-coherent
// local L2 so peer XCDs can see it after the barrier.
__device__ __forceinline__ void store_dc(float* p, float v) {
    __hip_atomic_store(p, v, __ATOMIC_RELAXED, __HIP_MEMORY_SCOPE_AGENT);
}

// Device-coherent loads: agent-scope relaxed atomics bypass stale L1/L2 and
// read the coherence point directly (replaces acquire-fence invalidation).
__device__ __forceinline__ float load_dc(const float* p) {
    return __hip_atomic_load(p, __ATOMIC_RELAXED, __HIP_MEMORY_SCOPE_AGENT);
}
__device__ __forceinline__ float4 load_dc4(const float4* p) {
    const unsigned long long* q = (const unsigned long long*)p;
    unsigned long long a = __hip_atomic_load(q,     __ATOMIC_RELAXED, __HIP_MEMORY_SCOPE_AGENT);
    unsigned long long b = __hip_atomic_load(q + 1, __ATOMIC_RELAXED, __HIP_MEMORY_SCOPE_AGENT);
    float4 r;
    ((unsigned long long*)&r)[0] = a;
    ((unsigned long long*)&r)[1] = b;
    return r;
}

// Two-level tree grid barrier, monotonic & relative (no reset, no memset).
// Group counters advance by exactly 16 per phase and root by NGROUPS per
// phase, and every launch completes all its phases -> at launch entry all
// counters sit at multiples of 16, so "last arriver" tests are (x & 15)==15.
// Release is a counter incremented once per completed phase; blocks wait for
// release >= R0 + phase (wrap-safe compare). R0 is read by thread 0 at kernel
// entry: release for this launch's phase 1 cannot advance until this block
// itself arrives, which is after the read (and the read is drained by the
// first __syncthreads inside build_cells before any arrival).
__device__ __forceinline__ void grid_barrier(unsigned R0, unsigned phase) {
    __syncthreads();
    if (threadIdx.x == 0) {
        const unsigned g = (unsigned)blockIdx.x >> 4;   // 16 blocks per group
        unsigned a = __hip_atomic_fetch_add(&bar_dev[g * BAR_STRIDE], 1u,
                                            __ATOMIC_RELAXED, __HIP_MEMORY_SCOPE_AGENT);
        if ((a & 15u) == 15u) {                         // last arriver of this group
            unsigned r = __hip_atomic_fetch_add(&bar_dev[NGROUPS * BAR_STRIDE], 1u,
                                                __ATOMIC_RELAXED, __HIP_MEMORY_SCOPE_AGENT);
            if ((r & (NGROUPS - 1u)) == NGROUPS - 1u)   // last group overall
                __hip_atomic_fetch_add(&bar_dev[(NGROUPS + 1u) * BAR_STRIDE], 1u,
                                       __ATOMIC_RELAXED, __HIP_MEMORY_SCOPE_AGENT);
        }
        while ((int)(__hip_atomic_load(&bar_dev[(NGROUPS + 1u) * BAR_STRIDE],
                                       __ATOMIC_RELAXED, __HIP_MEMORY_SCOPE_AGENT)
                     - (R0 + phase)) < 0) {
            __builtin_amdgcn_s_sleep(1);
        }
    }
    __syncthreads();
}

__device__ __forceinline__ int cell_coord(float v) {
    int c = (int)floorf(v * 10.f);
    return min(max(c, 0), NC - 1);
}
__device__ __forceinline__ int cell_id(float x, float y, float z) {
    return (cell_coord(x) * NC + cell_coord(y)) * NC + cell_coord(z);
}

// Per-block counting-sort cell list (AoS float4, parallel scan). Rebuilt every
// iteration (exact pair sets required — frozen-order approximation failed R10).
__device__ __forceinline__ int4 build_cells(float4 BX, float4 BY, float4 BZ,
                                            float4* ssp, unsigned* ccnt,
                                            unsigned* wtot, int tid) {
    ccnt[tid] = 0;
    __syncthreads();
    int c0 = cell_id(BX.x, BY.x, BZ.x);
    int c1 = cell_id(BX.y, BY.y, BZ.y);
    int c2 = cell_id(BX.z, BY.z, BZ.z);
    int c3 = cell_id(BX.w, BY.w, BZ.w);
    atomicAdd(&ccnt[c0], 1u); atomicAdd(&ccnt[c1], 1u);
    atomicAdd(&ccnt[c2], 1u); atomicAdd(&ccnt[c3], 1u);
    __syncthreads();
    // all-wave parallel exclusive scan over 1024 entries: thread t = entry t
    {
        const int l = tid & 63, w = tid >> 6;
        unsigned v = ccnt[tid];
        unsigned incl = v;
        for (int off = 1; off < 64; off <<= 1) {
            unsigned u = __shfl_up(incl, off);
            if (l >= off) incl += u;
        }
        if (l == 63) wtot[w] = incl;        // per-wave total
        unsigned excl = incl - v;
        __syncthreads();
        if (tid < 16) {                     // exclusive scan of 16 wave totals
            unsigned tv = wtot[tid];
            unsigned ti = tv;
            for (int off = 1; off < 16; off <<= 1) {
                unsigned u = __shfl_up(ti, off);
                if (tid >= off) ti += u;
            }
            wtot[tid] = ti - tv;
        }
        __syncthreads();
        ccnt[tid] = excl + wtot[w];         // global exclusive start
    }
    __syncthreads();
    int4 p;
    p.x = (int)atomicAdd(&ccnt[c0], 1u); ssp[p.x] = make_float4(BX.x, BY.x, BZ.x, 0.f);
    p.y = (int)atomicAdd(&ccnt[c1], 1u); ssp[p.y] = make_float4(BX.y, BY.y, BZ.y, 0.f);
    p.z = (int)atomicAdd(&ccnt[c2], 1u); ssp[p.z] = make_float4(BX.z, BY.z, BZ.z, 0.f);
    p.w = (int)atomicAdd(&ccnt[c3], 1u); ssp[p.w] = make_float4(BX.w, BY.w, BZ.w, 0.f);
    __syncthreads();          // ccnt now holds cell END offsets; sorted array ready
    return p;
}

// Per-lane run boundaries for the FLATTENED neighborhood walk: lanes are
// partitioned across the 9 (dx,dy) z-column runs (7 lanes per run; lane 63
// idle). Computed ONCE per iteration (ccnt is stable between builds) and
// reused for both the rho and delta walks.
__device__ __forceinline__ void walk_bounds(int cix, int ciy, int ciz,
                                            const unsigned* ccnt, int lane,
                                            int& wbeg, int& wend) {
    const int r = lane / 7;              // run 0..8 (lane 63 -> 9: idle)
    wbeg = 0; wend = 0;
    if (r < 9) {
        const int nx = cix + (r / 3) - 1;
        const int ny = ciy + (r % 3) - 1;
        if ((unsigned)nx < (unsigned)NC && (unsigned)ny < (unsigned)NC) {
            const int zlo = max(ciz - 1, 0), zhi = min(ciz + 1, NC - 1);
            const int cb  = (nx * NC + ny) * NC;
            const int cA  = cb + zlo, cB = cb + zhi;
            wbeg = (cA > 0) ? (int)ccnt[cA - 1] : 0;
            wend = (int)ccnt[cB];
        }
    }
}

// ---------------- single fused kernel ----------------
// 256 blocks x 1024 threads (16 waves), 1 particle/wave, ~132 KB static LDS
// -> 1 block/CU, grid 256 = CU count, co-resident (plain launch).

__global__ __launch_bounds__(NT) void k_fused(const float4* __restrict__ locs4,
                                              const float4* __restrict__ vel4,
                                              const float* __restrict__ locs,
                                              const float* __restrict__ vel,
                                              float* __restrict__ px, float* __restrict__ py,
                                              float* __restrict__ pz,
                                              float* __restrict__ lam,
                                              float* __restrict__ vnx, float* __restrict__ vny,
                                              float* __restrict__ vnz,
                                              float* __restrict__ out, int n) {
    __shared__ float4 ssp[NMAX];        // 64 KB sorted (x,y,z,lam)
    __shared__ float4 svp[NMAX];        // 64 KB sorted (vx,vy,vz,0) for visc
    __shared__ unsigned ccnt[NT];       // 4 KB cell table (+pad)
    __shared__ unsigned wtot[16];       // wave totals for scan

    const int tid  = threadIdx.x;
    const int lane = tid & 63;
    const int wave = tid >> 6;
    const int i    = blockIdx.x * 16 + wave;            // owned particle (original idx)
    const int wo   = lane - (lane / 7) * 7;             // offset within walk run
    unsigned phase = 0;
    (void)n;

    // Read release base BEFORE any arrival (drained by first __syncthreads).
    unsigned R0 = 0;
    if (tid == 0)
        R0 = __hip_atomic_load(&bar_dev[(NGROUPS + 1u) * BAR_STRIDE],
                               __ATOMIC_RELAXED, __HIP_MEMORY_SCOPE_AGENT);

    // ---- predict (registers) for this thread's 4 particles; build cell list 1 ----
    float4 BX, BY, BZ;
    {
        float lo[12], ve[12];
        *(float4*)&lo[0] = locs4[3*tid];   *(float4*)&lo[4] = locs4[3*tid+1]; *(float4*)&lo[8] = locs4[3*tid+2];
        *(float4*)&ve[0] = vel4[3*tid];    *(float4*)&ve[4] = vel4[3*tid+1];  *(float4*)&ve[8] = vel4[3*tid+2];
        float P[12];
#pragma unroll
        for (int q = 0; q < 4; ++q) {
            float vx = ve[3*q], vy = ve[3*q+1] - 9.8f * DT, vz = ve[3*q+2];
            float vv = sqrtf(vx*vx + vy*vy + vz*vz);
            float s  = fminf(MAX_VEL / (vv + 1e-4f), 1.0f);
            P[3*q]   = lo[3*q]   + DT * vx * s;
            P[3*q+1] = lo[3*q+1] + DT * vy * s;
            P[3*q+2] = lo[3*q+2] + DT * vz * s;
        }
        BX = make_float4(P[0], P[3], P[6], P[9]);
        BY = make_float4(P[1], P[4], P[7], P[10]);
        BZ = make_float4(P[2], P[5], P[8], P[11]);
    }
    int4 p = build_cells(BX, BY, BZ, ssp, ccnt, wtot, tid);

    // own predicted position (identical expression tree -> identical rounding)
    float xi, yi, zi;
    {
        float vx = vel[3*i], vy = vel[3*i+1] - 9.8f * DT, vz = vel[3*i+2];
        float vv = sqrtf(vx*vx + vy*vy + vz*vz);
        float s  = fminf(MAX_VEL / (vv + 1e-4f), 1.0f);
        xi = locs[3*i]   + DT * vx * s;
        yi = locs[3*i+1] + DT * vy * s;
        zi = locs[3*i+2] + DT * vz * s;
    }

    for (int it = 0; it < 3; ++it) {
        const bool last = (it == 2);

        // per-iteration walk boundaries (reused by rho AND delta)
        int wbeg, wend;
        walk_bounds(cell_coord(xi), cell_coord(yi), cell_coord(zi), ccnt, lane, wbeg, wend);

        // ---- rho: flattened neighbor-cell walk ----
        float S = 0.f;
        for (int j = wbeg + wo; j < wend; j += 7) {
            float4 P = ssp[j];
            float ddx = xi - P.x, ddy = yi - P.y, ddz = zi - P.z;
            float d2 = fmaf(ddx,ddx,EPS); d2 = fmaf(ddy,ddy,d2); d2 = fmaf(ddz,ddz,d2);
            float t  = fmaxf(RADIUS - __builtin_amdgcn_sqrtf(d2), 0.f);
            S = fmaf(t*t, t, S);
        }
        for (int off = 32; off > 0; off >>= 1) S += __shfl_down(S, off);
        if (lane == 0) {
            const float ts  = RADIUS - __builtin_amdgcn_sqrtf(EPS);  // exact self-term
            const float TS3 = ts*ts*ts;
            const float k3  = 3.f * SPIKY_C * STIFFNESS;             // L = -3C*lam
            store_dc(&lam[i], k3 * (SPIKY_C * (S - TS3) - DENSITY_REST));
        }
        grid_barrier(R0, ++phase);

        // ---- stage L into .w of sorted slots (coherent sc1 reads) ----
        {
            float4 l4 = load_dc4(((const float4*)lam) + tid);
            ssp[p.x].w = l4.x; ssp[p.y].w = l4.y; ssp[p.z].w = l4.z; ssp[p.w].w = l4.w;
        }
        float Li = load_dc(&lam[i]);
        __syncthreads();

        // ---- delta: same boundaries, (x,y,z,L) in one b128 ----
        float ax = 0.f, ay = 0.f, az = 0.f;
        for (int j = wbeg + wo; j < wend; j += 7) {
            float4 P = ssp[j];
            float ddx = xi - P.x, ddy = yi - P.y, ddz = zi - P.z;
            float d2 = fmaf(ddx,ddx,EPS); d2 = fmaf(ddy,ddy,d2); d2 = fmaf(ddz,ddz,d2);
            float rinv = __builtin_amdgcn_rsqf(d2);
            float t  = fmaxf(RADIUS - d2*rinv, 0.f);
            float cf = (Li + P.w) * (t*t) * rinv;
            ax = fmaf(cf, ddx, ax); ay = fmaf(cf, ddy, ay); az = fmaf(cf, ddz, az);
        }
        for (int off = 32; off > 0; off >>= 1) {
            ax += __shfl_down(ax, off); ay += __shfl_down(ay, off); az += __shfl_down(az, off);
        }
        if (lane == 0) {
            float nx = xi + ax, ny = yi + ay, nz = zi + az;
            store_dc(&px[i], nx); store_dc(&py[i], ny); store_dc(&pz[i], nz);
            if (last) {
                out[3*i+0] = nx; out[3*i+1] = ny; out[3*i+2] = nz;
                store_dc(&vnx[i], (nx - locs[3*i+0]) * (1.0f/DT));
                store_dc(&vny[i], (ny - locs[3*i+1]) * (1.0f/DT));
                store_dc(&vnz[i], (nz - locs[3*i+2]) * (1.0f/DT));
            }
        }
        grid_barrier(R0, ++phase);

        // ---- rebuild cell list from updated pred (coherent sc1 reads) ----
        BX = load_dc4(((const float4*)px) + tid);
        BY = load_dc4(((const float4*)py) + tid);
        BZ = load_dc4(((const float4*)pz) + tid);
        p  = build_cells(BX, BY, BZ, ssp, ccnt, wtot, tid);
        xi = load_dc(&px[i]); yi = load_dc(&py[i]); zi = load_dc(&pz[i]);
    }

    // ---- XSPH viscosity: stage new_vel sorted (AoS), then flattened walk ----
    {
        float4 a4 = load_dc4(((const float4*)vnx) + tid);
        float4 b4 = load_dc4(((const float4*)vny) + tid);
        float4 c4 = load_dc4(((const float4*)vnz) + tid);
        svp[p.x] = make_float4(a4.x, b4.x, c4.x, 0.f);
        svp[p.y] = make_float4(a4.y, b4.y, c4.y, 0.f);
        svp[p.z] = make_float4(a4.z, b4.z, c4.z, 0.f);
        svp[p.w] = make_float4(a4.w, b4.w, c4.w, 0.f);
    }
    const float vix = load_dc(&vnx[i]), viy = load_dc(&vny[i]), viz = load_dc(&vnz[i]);
    __syncthreads();

    int wbeg, wend;
    walk_bounds(cell_coord(xi), cell_coord(yi), cell_coord(zi), ccnt, lane, wbeg, wend);
    float sw = 0.f, sax = 0.f, say = 0.f, saz = 0.f;
    for (int j = wbeg + wo; j < wend; j += 7) {
        float4 P = ssp[j];
        float4 V = svp[j];
        float ddx = xi - P.x, ddy = yi - P.y, ddz = zi - P.z;
        float d2 = fmaf(ddx,ddx,EPS); d2 = fmaf(ddy,ddy,d2); d2 = fmaf(ddz,ddz,d2);
        float t  = fmaxf(RADIUS - __builtin_amdgcn_sqrtf(d2), 0.f);
        float w  = t*t*t;
        sw += w;
        sax = fmaf(w, V.x, sax); say = fmaf(w, V.y, say); saz = fmaf(w, V.z, saz);
    }
    for (int off = 32; off > 0; off >>= 1) {
        sw  += __shfl_down(sw, off);  sax += __shfl_down(sax, off);
        say += __shfl_down(say, off); saz += __shfl_down(saz, off);
    }
    if (lane == 0) {
        constexpr float K = VISCOSITY * DT / DENSITY_REST;
        const float KC = K * SPIKY_C;   // C folded here; self-term cancels exactly
        float nvx = vix + KC * (sax - sw * vix);
        float nvy = viy + KC * (say - sw * viy);
        float nvz = viz + KC * (saz - sw * viz);
        float vv = sqrtf(nvx*nvx + nvy*nvy + nvz*nvz);
        float s  = fminf(MAX_VEL / (vv + 1e-4f), 1.0f);
        out[3*NMAX + 3*i + 0] = nvx * s;
        out[3*NMAX + 3*i + 1] = nvy * s;
        out[3*NMAX + 3*i + 2] = nvz * s;
    }
}

extern "C" void kernel_launch(void* const* d_in, const int* in_sizes, int n_in,
                              void* d_out, int out_size, void* d_ws, size_t ws_size,
                              hipStream_t stream) {
    const float* locs = (const float*)d_in[0];
    const float* vel  = (const float*)d_in[1];
    const float4* locs4 = (const float4*)locs;
    const float4* vel4  = (const float4*)vel;
    float* out = (float*)d_out;
    int n = in_sizes[0] / 3;   // 4096

    float* w = (float*)d_ws;
    float* px  = w;        float* py  = px + n;   float* pz  = py + n;
    float* lam = pz + n;
    float* vnx = lam + n;  float* vny = vnx + n;  float* vnz = vny + n;

    int nb = n / 16;   // 16 waves/block, 1 particle/wave -> 256 blocks

    k_fused<<<dim3(nb), dim3(NT), 0, stream>>>(locs4, vel4, locs, vel,
                                               px, py, pz, lam,
                                               vnx, vny, vnz,
                                               out, n);
}